// Round 12
// baseline (77.304 us; speedup 1.0000x reference)
//
#include <hip/hip_runtime.h>
#include <hip/hip_fp8.h>
#include <cstdint>

typedef unsigned short u16;
typedef unsigned int   u32;
typedef unsigned long long u64;
typedef float  f32x16 __attribute__((ext_vector_type(16)));
typedef float  f32x4  __attribute__((ext_vector_type(4)));
typedef u32    u32x2  __attribute__((ext_vector_type(2)));
typedef u32    u32x4  __attribute__((ext_vector_type(4)));

#define OUT1 984064   // 16*248*248
#define OUT2 350464   // 16*16*37*37

// workspace layout (bytes) — fp8 K=32-per-load edition
// Ximg5: [d:16][vp:16][row:248][n:16][c:16] fp8   (col = d + 16*vp + c)
#define XD5        1015808           // 16 vp * 63488
#define TMPL_OFFB  16252928
// Tmpl5: [vp:14][row:216][o:16][c:16] fp8         (col = 16*vp + c, zero-pad)
#define PART_OFFB  17027072
#define PART_ELEMS (6*OUT2)          // [3 uq][2 gp] slabs, layout [r][n][o]
#define XC_OFFB    25438208          // Xc: [c:16][row:248][col:272] bf16

// ---------------- k1: f32 conv + relu + normalize -> out1 + canonical bf16 Xc
__global__ __launch_bounds__(256) void k1_conv(
    const float* __restrict__ x, const float* __restrict__ ft,
    const float* __restrict__ fnt, float* __restrict__ out1,
    u16* __restrict__ Xc) {
  __shared__ float xt[24][25];
  __shared__ float wsm[1296];
  const int tid = threadIdx.x;
  const int lx = tid & 15, ly = tid >> 4;
  const int bx = blockIdx.x, by = blockIdx.y;
  for (int idx = tid; idx < 1296; idx += 256) {   // effw built in-block
    int c = idx / 81, s = idx - (idx / 81) * 81;
    wsm[idx] = (c < 8) ? 0.5f * (ft[c*162 + s] + ft[c*162 + 81 + s])
                       : fnt[(c-8)*81 + s];
  }
  for (int idx = tid; idx < 576; idx += 256) {
    int ry = idx / 24, rx = idx - ry * 24;
    int gy = by*16 + ry; gy = gy > 255 ? 255 : gy;
    int gx = bx*16 + rx; gx = gx > 255 ? 255 : gx;
    xt[ry][rx] = x[gy*256 + gx];
  }
  __syncthreads();
  const int xg = bx*16 + lx, yg = by*16 + ly;
  if (yg >= 248) return;
  float s[16];
#pragma unroll
  for (int c = 0; c < 16; ++c) s[c] = 0.f;
  const bool valid = (xg < 248);
  if (valid) {
#pragma unroll
    for (int u = 0; u < 9; ++u)
#pragma unroll
      for (int v = 0; v < 9; ++v) {
        float xv = xt[ly + u][lx + v];
#pragma unroll
        for (int c = 0; c < 16; ++c)
          s[c] = __builtin_fmaf(xv, wsm[c*81 + u*9 + v], s[c]);
      }
    float sum = 2.2204460492503131e-16f;  // EPS, matches reference
#pragma unroll
    for (int c = 0; c < 16; ++c) { s[c] = s[c] > 0.f ? s[c] : 0.f; sum += s[c]; }
    float inv = 1.f / sum;
#pragma unroll
    for (int c = 0; c < 16; ++c) s[c] *= inv;
  }
#pragma unroll
  for (int c = 0; c < 16; ++c) {
    u16 hb = 0;
    if (valid) {
      out1[c*61504 + yg*248 + xg] = s[c];
      u32 ub = __builtin_bit_cast(u32, s[c]);
      hb = (u16)((ub + 0x7fffu + ((ub >> 16) & 1u)) >> 16);  // bf16 RNE
    }
    Xc[(c*248 + yg)*272 + xg] = hb;   // xg<=271 always; cols 248..271 zeros
  }
}

// ---------------- k1b: Xc(bf16) -> fp8 Ximg5 (16 shifts) + Tmpl5; zero partial
__device__ __forceinline__ u32 pk4_fp8(u32 b0, u32 b1) {
  // two u32 of packed bf16 (4 values) -> 4 fp8 e4m3 bytes (RNE via HIP type)
  float f0 = __builtin_bit_cast(float, b0 << 16);
  float f1 = __builtin_bit_cast(float, b0 & 0xFFFF0000u);
  float f2 = __builtin_bit_cast(float, b1 << 16);
  float f3 = __builtin_bit_cast(float, b1 & 0xFFFF0000u);
  __hip_fp8_e4m3 e0(f0), e1(f1), e2(f2), e3(f3);
  return (u32)e0.__x | ((u32)e1.__x << 8) | ((u32)e2.__x << 16) | ((u32)e3.__x << 24);
}

__global__ __launch_bounds__(256) void k1b_expand(
    const u16* __restrict__ Xc, unsigned char* __restrict__ ws8,
    float* __restrict__ partial) {
  const int cid = blockIdx.x*256 + threadIdx.x;
  for (int z = cid; z < PART_ELEMS; z += gridDim.x*256) partial[z] = 0.f;
  const u32* src = (const u32*)Xc;
  if (cid < 1015808) {                 // Ximg5: 16d*16vp*248row*16n chunks of 16B
    int n  = cid & 15;
    int r1 = cid >> 4;
    int row = r1 % 248;
    int r2  = r1 / 248;
    int vp  = r2 & 15;
    int d   = r2 >> 4;                 // 0..15
    int col0 = d + 16*vp;              // cols col0..col0+15 of Xc row
    int so = (n*248 + row)*136 + (col0 >> 1);
    u32 a[9], b[8];
#pragma unroll
    for (int i = 0; i < 9; ++i) a[i] = src[so + i];
    if (d & 1) {                       // odd shift: 16-bit funnel
#pragma unroll
      for (int i = 0; i < 8; ++i) b[i] = (a[i] >> 16) | (a[i+1] << 16);
    } else {
#pragma unroll
      for (int i = 0; i < 8; ++i) b[i] = a[i];
    }
    u32x4 v = { pk4_fp8(b[0], b[1]), pk4_fp8(b[2], b[3]),
                pk4_fp8(b[4], b[5]), pk4_fp8(b[6], b[7]) };
    *(u32x4*)(ws8 + ((size_t)((d*16 + vp)*248 + row))*256 + n*16) = v;
  } else if (cid < 1015808 + 48384) {  // Tmpl5: 14vp*216row*16o chunks of 16B
    int t  = cid - 1015808;
    int o  = t & 15;
    int r1 = t >> 4;
    int tr = r1 % 216;
    int vp = r1 / 216;                 // 0..13
    u32x4 v = {0u, 0u, 0u, 0u};
    if (tr < 212) {
      int so = (o*248 + tr + 18)*136 + ((18 + 16*vp) >> 1);
      u32 b[8];
#pragma unroll
      for (int i = 0; i < 8; ++i) b[i] = src[so + i];
      v[0] = pk4_fp8(b[0], b[1]);
      if (vp < 13) {                   // rel cols >=212 are pad (vp13: c>=4)
        v[1] = pk4_fp8(b[2], b[3]);
        v[2] = pk4_fp8(b[4], b[5]);
        v[3] = pk4_fp8(b[6], b[7]);
      }
    }
    *(u32x4*)(ws8 + TMPL_OFFB + ((size_t)(vp*216 + tr))*256 + o*16) = v;
  }
}

// ---------------- k2: fp8 MFMA correlation, K=32/load, sc0 L1-bypass ---------
// r11 structure. New: (a) sc0 on all loads — L1 miss-evict so lines come from
// L2 without the L1 fill-path serialization (every line is a provable L1 miss;
// clean retest of r5's confounded hypothesis; line-count 1232/wave is the one
// invariant matching the ~40us plateau at ~8cy/line L1 fill). (b) emit to
// transposed slab layout [r=i*37+j][n][o]: 11x 1KB contiguous stores per block
// (was 2816 scattered 4B at stride 5476 -> ~37MB of 32B-sector HBM traffic).
#define F_LD(k,m,c) fl[(k)*1024 + (((m)&3) + 4*((m)>>3))*64 + ((c) + 32*(((m)>>2)&1))]

#define LD_A(q,SO) asm volatile("buffer_load_dwordx4 %0, %1, %2, %3 offen sc0" \
  : "=v"(A[q]) : "v"(voffA[q]), "s"(srdA), "s"(SO));
#define LD_B(t,SO) asm volatile("buffer_load_dwordx4 %0, %1, %2, %3 offen sc0" \
  : "=v"(B[t]) : "v"(voffB[t]), "s"(srdB), "s"(SO));
#define WT(N,X,Y) asm volatile("s_waitcnt vmcnt(" #N ")" : "+v"(X), "+v"(Y) ::);
#define LO8(V) __builtin_bit_cast(long, (u32x2){(V)[0], (V)[1]})
#define HI8(V) __builtin_bit_cast(long, (u32x2){(V)[2], (V)[3]})
#define MF10(t) { long _bl = LO8(B[t]), _bh = HI8(B[t]); \
  acc[0]=__builtin_amdgcn_mfma_f32_32x32x16_fp8_fp8(LO8(A[t+0]),_bl,acc[0],0,0,0); \
  acc[1]=__builtin_amdgcn_mfma_f32_32x32x16_fp8_fp8(LO8(A[t+1]),_bl,acc[1],0,0,0); \
  acc[2]=__builtin_amdgcn_mfma_f32_32x32x16_fp8_fp8(LO8(A[t+2]),_bl,acc[2],0,0,0); \
  acc[3]=__builtin_amdgcn_mfma_f32_32x32x16_fp8_fp8(LO8(A[t+3]),_bl,acc[3],0,0,0); \
  acc[4]=__builtin_amdgcn_mfma_f32_32x32x16_fp8_fp8(LO8(A[t+4]),_bl,acc[4],0,0,0); \
  acc[0]=__builtin_amdgcn_mfma_f32_32x32x16_fp8_fp8(HI8(A[t+0]),_bh,acc[0],0,0,0); \
  acc[1]=__builtin_amdgcn_mfma_f32_32x32x16_fp8_fp8(HI8(A[t+1]),_bh,acc[1],0,0,0); \
  acc[2]=__builtin_amdgcn_mfma_f32_32x32x16_fp8_fp8(HI8(A[t+2]),_bh,acc[2],0,0,0); \
  acc[3]=__builtin_amdgcn_mfma_f32_32x32x16_fp8_fp8(HI8(A[t+3]),_bh,acc[3],0,0,0); \
  acc[4]=__builtin_amdgcn_mfma_f32_32x32x16_fp8_fp8(HI8(A[t+4]),_bh,acc[4],0,0,0); }

__global__ __launch_bounds__(256, 2) void k2_corr(
    const unsigned char* __restrict__ Ximg5, const unsigned char* __restrict__ Tmpl5,
    float* __restrict__ partial) {
  __shared__ float fl[5120];
  const int bid = blockIdx.x;
  const int jl  = bid & 7;            // j low bits == XCD (pinning heuristic)
  const int m0  = bid >> 3;           // 0..59
  const int jj  = m0 % 5;
  const int cmb = m0 / 5;             // 0..11
  const int g   = cmb & 3;
  const int uq  = cmb >> 2;           // 0..2
  const int j   = jl + 8*jj;
  if (j >= 37) return;                // 36 idle pad blocks
  const int U0  = 72*uq;
  const int R0  = 10*g + U0;
  const int tid  = threadIdx.x;
  const int lane = tid & 63;
  const int w    = tid >> 6;
  const int fn16 = lane & 15;
  const int fuu  = (lane >> 4) & 1;
  const int fg   = lane >> 5;

  // SRDs (uniform bases); per-lane 32-bit voffsets; s advance rides in soffset
  u64 pa = (u64)(Ximg5 + (j & 15)*XD5 + (j >> 4)*63488);
  u64 pb = (u64)(Tmpl5);
  u32x4 srdA = { (u32)pa, (u32)(pa >> 32), 0xFFFFFFFFu, 0x00020000u };
  u32x4 srdB = { (u32)pb, (u32)(pb >> 32), 0xFFFFFFFFu, 0x00020000u };
  int voffA[13], voffB[9];
#pragma unroll
  for (int q = 0; q < 13; ++q) {
    int r = R0 + fuu + 18*w + 2*q;
    if (r > 247) r = 247;             // clamped rows only ever pair with zero B
    voffA[q] = fg*63488 + fn16*16 + r*256;
  }
#pragma unroll
  for (int t = 0; t < 9; ++t)
    voffB[t] = fg*55296 + fn16*16 + (U0 + fuu + 18*w + 2*t)*256;

  f32x16 acc[5];
#pragma unroll
  for (int k = 0; k < 5; ++k)
#pragma unroll
    for (int q = 0; q < 16; ++q) acc[k][q] = 0.f;

  u32x4 A[13], B[9];
  // prologue (s=0), issue order P0..P8 (the vmcnt ladder depends on it)
  { int sa = 0, sb = 0;
    LD_A(0,sa) LD_B(0,sb) LD_A(1,sa) LD_B(1,sb)
    LD_A(2,sa) LD_B(2,sb) LD_A(3,sa) LD_B(3,sb)
    LD_A(4,sa) LD_B(4,sb) LD_A(5,sa) LD_B(5,sb)
    LD_A(6,sa) LD_B(6,sb) LD_A(7,sa) LD_B(7,sb)
    LD_A(8,sa) LD_A(9,sa) LD_A(10,sa) LD_A(11,sa) LD_A(12,sa) LD_B(8,sb) }

#pragma unroll 1
  for (int s = 0; s < 6; ++s) {       // consume double-step s, prefetch s+1
    const int sa = (s + 1)*126976, sb = (s + 1)*110592;
    WT(13, A[4],  B[0])  MF10(0) LD_A(0,sa) LD_B(0,sb)
    WT(13, A[5],  B[1])  MF10(1) LD_A(1,sa) LD_B(1,sb)
    WT(13, A[6],  B[2])  MF10(2) LD_A(2,sa) LD_B(2,sb)
    WT(13, A[7],  B[3])  MF10(3) LD_A(3,sa) LD_B(3,sb)
    WT(13, A[8],  B[4])  MF10(4) LD_A(4,sa) LD_B(4,sb)
    WT(14, A[9],  B[5])  MF10(5) LD_A(5,sa) LD_B(5,sb)
    WT(15, A[10], B[6])  MF10(6) LD_A(6,sa) LD_B(6,sb)
    WT(16, A[11], B[7])  MF10(7) LD_A(7,sa) LD_B(7,sb)
    WT(16, A[12], B[8])  MF10(8)
    LD_A(8,sa) LD_A(9,sa) LD_A(10,sa) LD_A(11,sa) LD_A(12,sa) LD_B(8,sb)
  }
  // tail: s=6, drain ladder
  WT(13, A[4],  B[0])  MF10(0)
  WT(11, A[5],  B[1])  MF10(1)
  WT(9,  A[6],  B[2])  MF10(2)
  WT(7,  A[7],  B[3])  MF10(3)
  WT(5,  A[8],  B[4])  MF10(4)
  WT(4,  A[9],  B[5])  MF10(5)
  WT(3,  A[10], B[6])  MF10(6)
  WT(2,  A[11], B[7])  MF10(7)
  WT(0,  A[12], B[8])  MF10(8)
  __syncthreads();

  // deterministic cross-wave fold in LDS (waves add sequentially)
  for (int z = tid; z < 5120; z += 256) fl[z] = 0.f;
  __syncthreads();
  for (int ww = 0; ww < 4; ++ww) {
    if (w == ww) {
#pragma unroll
      for (int k = 0; k < 5; ++k) {
        if (!(g == 3 && k == 4)) {    // g3 chain 4 duplicates i0=36: exclude
#pragma unroll
          for (int q = 0; q < 16; ++q)
            fl[k*1024 + q*64 + lane] += acc[k][q];
        }
      }
    }
    __syncthreads();
  }

  // emit 11 rows: slab layout [r=i*37+j][n][o] -> 1KB contiguous per row
  const int n = (tid >> 4) & 15;
  const int o = tid & 15;
  float* slab = partial + (uq*2 + (g & 1)) * OUT2;
  for (int ii = 0; ii < 11; ++ii) {
    const int i = 10*g - 1 + ii;
    if (i < 0 || i >= 37) continue;
    const int dd = ii - 1;
    float v;
    if (!(dd & 1)) {                  // diag: (uu,p)=(0,0)+(1,1)
      const int k = dd >> 1;
      v = F_LD(k, n, o) + F_LD(k, n+16, o+16);
    } else {
      v = 0.f;
      if (dd >= 1) v += F_LD((dd-1) >> 1, n+16, o);   // (1,0) from left chain
      const int kr = (dd+1) >> 1;
      if (kr <= 4) v += F_LD(kr, n, o+16);            // (0,1) from right chain
    }
    slab[(i*37 + j)*256 + tid] = v;   // tid == n*16+o -> fully coalesced
  }
}

// ---------------- k3: reduce 6 slabs [r][n][o] + scale, transpose to out2 ----
__global__ __launch_bounds__(256) void k3_reduce(
    const float* __restrict__ partial, float* __restrict__ out2) {
  const int r0 = blockIdx.x * 8;      // 172 blocks x 8 r-values
  const int tid = threadIdx.x;        // tid = n*16 + o
  float v[8];
#pragma unroll
  for (int rr = 0; rr < 8; ++rr) v[rr] = 0.f;
#pragma unroll
  for (int t = 0; t < 6; ++t)
#pragma unroll
    for (int rr = 0; rr < 8; ++rr) {
      int r = r0 + rr;
      if (r < 1369) v[rr] += partial[t*OUT2 + r*256 + tid];  // contiguous/inst
    }
  const int n = tid >> 4, o = tid & 15;
  const float sc = 1.0f / 44944.0f;
  float* dst = out2 + (o*16 + n)*1369;
#pragma unroll
  for (int rr = 0; rr < 8; ++rr) {    // 8 consecutive floats per thread (32B)
    int r = r0 + rr;
    if (r < 1369) dst[r] = v[rr] * sc;
  }
}

extern "C" void kernel_launch(void* const* d_in, const int* in_sizes, int n_in,
                              void* d_out, int out_size, void* d_ws, size_t ws_size,
                              hipStream_t stream) {
  (void)in_sizes; (void)n_in; (void)out_size; (void)ws_size;
  const float* x   = (const float*)d_in[0];
  const float* ft  = (const float*)d_in[1];
  const float* fnt = (const float*)d_in[2];
  float* out = (float*)d_out;
  char*  ws  = (char*)d_ws;
  unsigned char* Ximg5 = (unsigned char*)ws;
  unsigned char* Tmpl5 = (unsigned char*)(ws + TMPL_OFFB);
  float* partial = (float*)(ws + PART_OFFB);
  u16*   Xc      = (u16*)(ws + XC_OFFB);

  k1_conv<<<dim3(17, 16), 256, 0, stream>>>(x, ft, fnt, out, Xc);
  k1b_expand<<<4157, 256, 0, stream>>>(Xc, (unsigned char*)ws, partial);
  k2_corr<<<480, 256, 0, stream>>>(Ximg5, Tmpl5, partial);
  k3_reduce<<<172, 256, 0, stream>>>(partial, out + OUT1);
}

// Round 13
// 75.679 us; speedup vs baseline: 1.0215x; 1.0215x over previous
//
#include <hip/hip_runtime.h>
#include <hip/hip_fp8.h>
#include <cstdint>

typedef unsigned short u16;
typedef unsigned int   u32;
typedef unsigned long long u64;
typedef float  f32x16 __attribute__((ext_vector_type(16)));
typedef float  f32x4  __attribute__((ext_vector_type(4)));
typedef u32    u32x2  __attribute__((ext_vector_type(2)));
typedef u32    u32x4  __attribute__((ext_vector_type(4)));

#define OUT1 984064   // 16*248*248
#define OUT2 350464   // 16*16*37*37

// workspace layout (bytes) — fp8 edition (r8 layout), 12 slabs
// Ximg3: [d:8][vb:32][row:248][n:16][c:8] fp8  (col = d + 8*vb + c)
#define XD_STRIDE  1015808           // 32 vb * 31744
#define TMPL_OFFB  8126464
// Tmpl3: [vb:28][row:216][o:16][c:8] fp8       (col = 8*vb + c, zero-padded)
#define PART_OFFB  8900608
#define PART_ELEMS (12*OUT2)         // [2 svh][3 uq][2 gp] partial slabs
#define XC_OFFB    25722880          // Xc: [c:16][row:248][col:264] bf16

// ---------------- k1: f32 conv + relu + normalize -> out1 + canonical bf16 Xc
__global__ __launch_bounds__(256) void k1_conv(
    const float* __restrict__ x, const float* __restrict__ ft,
    const float* __restrict__ fnt, float* __restrict__ out1,
    u16* __restrict__ Xc) {
  __shared__ float xt[24][25];
  __shared__ float wsm[1296];
  const int tid = threadIdx.x;
  const int lx = tid & 15, ly = tid >> 4;
  const int bx = blockIdx.x, by = blockIdx.y;
  for (int idx = tid; idx < 1296; idx += 256) {   // effw built in-block
    int c = idx / 81, s = idx - (idx / 81) * 81;
    wsm[idx] = (c < 8) ? 0.5f * (ft[c*162 + s] + ft[c*162 + 81 + s])
                       : fnt[(c-8)*81 + s];
  }
  for (int idx = tid; idx < 576; idx += 256) {
    int ry = idx / 24, rx = idx - ry * 24;
    int gy = by*16 + ry; gy = gy > 255 ? 255 : gy;
    int gx = bx*16 + rx; gx = gx > 255 ? 255 : gx;
    xt[ry][rx] = x[gy*256 + gx];
  }
  __syncthreads();
  const int xg = bx*16 + lx, yg = by*16 + ly;
  if (yg >= 248) return;
  float s[16];
#pragma unroll
  for (int c = 0; c < 16; ++c) s[c] = 0.f;
  const bool valid = (xg < 248);
  if (valid) {
#pragma unroll
    for (int u = 0; u < 9; ++u)
#pragma unroll
      for (int v = 0; v < 9; ++v) {
        float xv = xt[ly + u][lx + v];
#pragma unroll
        for (int c = 0; c < 16; ++c)
          s[c] = __builtin_fmaf(xv, wsm[c*81 + u*9 + v], s[c]);
      }
    float sum = 2.2204460492503131e-16f;  // EPS, matches reference
#pragma unroll
    for (int c = 0; c < 16; ++c) { s[c] = s[c] > 0.f ? s[c] : 0.f; sum += s[c]; }
    float inv = 1.f / sum;
#pragma unroll
    for (int c = 0; c < 16; ++c) s[c] *= inv;
  }
#pragma unroll
  for (int c = 0; c < 16; ++c) {
    u16 hb = 0;
    if (valid) {
      out1[c*61504 + yg*248 + xg] = s[c];
      u32 ub = __builtin_bit_cast(u32, s[c]);
      hb = (u16)((ub + 0x7fffu + ((ub >> 16) & 1u)) >> 16);  // bf16 RNE
    }
    if (xg < 264) Xc[(c*248 + yg)*264 + xg] = hb;  // cols 248..263 get zeros
  }
}

// ---------------- k1b: Xc(bf16) -> fp8 Ximg3 (8 shifts) + Tmpl3; zero partial
__device__ __forceinline__ u32 pk4_fp8(u32 b0, u32 b1) {
  // two u32 of packed bf16 (4 values) -> 4 fp8 e4m3 bytes (RNE via HIP type)
  float f0 = __builtin_bit_cast(float, b0 << 16);
  float f1 = __builtin_bit_cast(float, b0 & 0xFFFF0000u);
  float f2 = __builtin_bit_cast(float, b1 << 16);
  float f3 = __builtin_bit_cast(float, b1 & 0xFFFF0000u);
  __hip_fp8_e4m3 e0(f0), e1(f1), e2(f2), e3(f3);
  return (u32)e0.__x | ((u32)e1.__x << 8) | ((u32)e2.__x << 16) | ((u32)e3.__x << 24);
}

__global__ __launch_bounds__(256) void k1b_expand(
    const u16* __restrict__ Xc, unsigned char* __restrict__ ws8,
    float* __restrict__ partial) {
  const int cid = blockIdx.x*256 + threadIdx.x;
  for (int z = cid; z < PART_ELEMS; z += gridDim.x*256) partial[z] = 0.f;
  const u32* src = (const u32*)Xc;
  if (cid < 507904) {                  // Ximg3: 8d*32vb*248row*8npair chunks of 16B
    int np = cid & 7;
    int r1 = cid >> 3;
    int row = r1 % 248;
    int r2  = r1 / 248;
    int vb  = r2 & 31;
    int d   = r2 >> 5;
    int colb = (d & ~1) + 8*vb;        // even -> 4B-aligned dword index
    u32 wout[4];
#pragma unroll
    for (int h = 0; h < 2; ++h) {
      int n = 2*np + h;
      int so = (n*248 + row)*132 + (colb >> 1);
      u32 a0 = src[so], a1 = src[so+1], a2 = src[so+2], a3 = src[so+3], a4 = src[so+4];
      u32 b0, b1, b2, b3;
      if (d & 1) {                     // odd shift: 16-bit funnel
        b0 = (a0 >> 16) | (a1 << 16); b1 = (a1 >> 16) | (a2 << 16);
        b2 = (a2 >> 16) | (a3 << 16); b3 = (a3 >> 16) | (a4 << 16);
      } else { b0 = a0; b1 = a1; b2 = a2; b3 = a3; }
      wout[h*2]     = pk4_fp8(b0, b1);
      wout[h*2 + 1] = pk4_fp8(b2, b3);
    }
    u32x4 v = { wout[0], wout[1], wout[2], wout[3] };
    *(u32x4*)(ws8 + ((size_t)((d*32 + vb)*248 + row))*128 + np*16) = v;
  } else if (cid < 507904 + 48384) {   // Tmpl3: 28vb*216row*8npair chunks of 16B
    int t  = cid - 507904;
    int np = t & 7;
    int r1 = t >> 3;
    int tr = r1 % 216;
    int vb = r1 / 216;
    u32x4 v = {0u, 0u, 0u, 0u};
    if (tr < 212 && vb < 27) {
#pragma unroll
      for (int h = 0; h < 2; ++h) {
        int n = 2*np + h;
        int so = (n*248 + tr + 18)*132 + ((18 + 8*vb) >> 1);
        u32 b0 = src[so], b1 = src[so+1], b2 = src[so+2], b3 = src[so+3];
        if (vb == 26) { b2 = 0u; b3 = 0u; }   // cols 212..215 are pad
        v[h*2]     = pk4_fp8(b0, b1);
        v[h*2 + 1] = pk4_fp8(b2, b3);
      }
    }
    *(u32x4*)(ws8 + TMPL_OFFB + ((size_t)(vb*216 + tr))*128 + np*16) = v;
  }
}

// ---------------- k2: fp8 MFMA correlation, counted-vmcnt, sv-SPLIT ---------
// r8-verified body (best total 68.9). ONE change this round: sv-range split in
// two halves -> 888 active blocks (~3.5/CU) + __launch_bounds__(256,3) -> 3
// waves/SIMD. Clean test of the TLP theory (r9's (256,3) was vacuous at 444
// blocks; r5's split was confounded by setprio-spill + sc0). Ledger of
// falsified k2 levers: bytes (r8), inst count (r11), depth (r10), registers
// (r7), schedule (r4/5), L1 policy (r12: sc0 = +7us), atomics (r9).
#define F_LD(k,m,c) fl[(k)*1024 + (((m)&3) + 4*((m)>>3))*64 + ((c) + 32*(((m)>>2)&1))]

#define LOADA(q,SO) asm volatile("buffer_load_dwordx2 %0, %1, %2, %3 offen" \
  : "=v"(A[q]) : "v"(voffA[q]), "s"(srdA), "s"(SO));
#define LOADB(t,SO) asm volatile("buffer_load_dwordx2 %0, %1, %2, %3 offen" \
  : "=v"(B[t]) : "v"(voffB[t]), "s"(srdB), "s"(SO));
#define WT(N,X,Y) asm volatile("s_waitcnt vmcnt(" #N ")" : "+v"(X), "+v"(Y) ::);
#define MF5(t) { long _bb = __builtin_bit_cast(long, B[t]); \
  acc[0]=__builtin_amdgcn_mfma_f32_32x32x16_fp8_fp8(__builtin_bit_cast(long,A[t+0]),_bb,acc[0],0,0,0); \
  acc[1]=__builtin_amdgcn_mfma_f32_32x32x16_fp8_fp8(__builtin_bit_cast(long,A[t+1]),_bb,acc[1],0,0,0); \
  acc[2]=__builtin_amdgcn_mfma_f32_32x32x16_fp8_fp8(__builtin_bit_cast(long,A[t+2]),_bb,acc[2],0,0,0); \
  acc[3]=__builtin_amdgcn_mfma_f32_32x32x16_fp8_fp8(__builtin_bit_cast(long,A[t+3]),_bb,acc[3],0,0,0); \
  acc[4]=__builtin_amdgcn_mfma_f32_32x32x16_fp8_fp8(__builtin_bit_cast(long,A[t+4]),_bb,acc[4],0,0,0); }

__global__ __launch_bounds__(256, 3) void k2_corr(
    const unsigned char* __restrict__ Ximg3, const unsigned char* __restrict__ Tmpl3,
    float* __restrict__ partial) {
  __shared__ float fl[5120];
  const int bid  = blockIdx.x;
  const int d    = bid & 7;           // shift residue (XCD pinning heuristic)
  const int m0   = bid >> 3;          // 0..119
  const int jq   = m0 % 5;
  const int rest = m0 / 5;            // 0..23
  const int svh  = rest / 12;         // 0..1  (v-range half)
  const int cmb  = rest % 12;
  const int g    = cmb & 3;
  const int uq   = cmb >> 2;          // 0..2
  const int j    = d + 8*jq;
  if (j >= 37) return;                // 72 idle pad blocks
  const int U0  = 72*uq;
  const int R0  = 10*g + U0;
  const int tid  = threadIdx.x;
  const int lane = tid & 63;
  const int w    = tid >> 6;
  const int fn16 = lane & 15;
  const int fuu  = (lane >> 4) & 1;
  const int fg   = lane >> 5;

  // SRDs (uniform bases); per-lane 32-bit voffsets; sv advance rides in soffset
  u64 pa = (u64)(Ximg3 + d*XD_STRIDE + jq*31744);
  u64 pb = (u64)(Tmpl3);
  u32x4 srdA = { (u32)pa, (u32)(pa >> 32), 0xFFFFFFFFu, 0x00020000u };
  u32x4 srdB = { (u32)pb, (u32)(pb >> 32), 0xFFFFFFFFu, 0x00020000u };
  int voffA[13], voffB[9];
#pragma unroll
  for (int q = 0; q < 13; ++q) {
    int r = R0 + fuu + 18*w + 2*q;
    if (r > 247) r = 247;             // clamped rows only ever pair with zero B
    voffA[q] = fg*31744 + fn16*8 + r*128;
  }
#pragma unroll
  for (int t = 0; t < 9; ++t)
    voffB[t] = fg*27648 + fn16*8 + (U0 + fuu + 18*w + 2*t)*128;

  f32x16 acc[5];
#pragma unroll
  for (int k = 0; k < 5; ++k)
#pragma unroll
    for (int q = 0; q < 16; ++q) acc[k][q] = 0.f;

  u32x2 A[13], B[9];
  const int sA0 = svh*444416, sB0 = svh*387072;   // 7 sv * (63488, 55296)
  // prologue (first sv of this half), issue order P0..P8
  { LOADA(0,sA0) LOADB(0,sB0) LOADA(1,sA0) LOADB(1,sB0)
    LOADA(2,sA0) LOADB(2,sB0) LOADA(3,sA0) LOADB(3,sB0)
    LOADA(4,sA0) LOADB(4,sB0) LOADA(5,sA0) LOADB(5,sB0)
    LOADA(6,sA0) LOADB(6,sB0) LOADA(7,sA0) LOADB(7,sB0)
    LOADA(8,sA0) LOADA(9,sA0) LOADA(10,sA0) LOADA(11,sA0) LOADA(12,sA0) LOADB(8,sB0) }

#pragma unroll 1
  for (int sv = 0; sv < 6; ++sv) {    // consume sv, prefetch sv+1 in place
    const int sa = sA0 + (sv + 1)*63488, sb = sB0 + (sv + 1)*55296;
    WT(13, A[4],  B[0])  MF5(0) LOADA(0,sa) LOADB(0,sb)
    WT(13, A[5],  B[1])  MF5(1) LOADA(1,sa) LOADB(1,sb)
    WT(13, A[6],  B[2])  MF5(2) LOADA(2,sa) LOADB(2,sb)
    WT(13, A[7],  B[3])  MF5(3) LOADA(3,sa) LOADB(3,sb)
    WT(13, A[8],  B[4])  MF5(4) LOADA(4,sa) LOADB(4,sb)
    WT(14, A[9],  B[5])  MF5(5) LOADA(5,sa) LOADB(5,sb)
    WT(15, A[10], B[6])  MF5(6) LOADA(6,sa) LOADB(6,sb)
    WT(16, A[11], B[7])  MF5(7) LOADA(7,sa) LOADB(7,sb)
    WT(16, A[12], B[8])  MF5(8)
    LOADA(8,sa) LOADA(9,sa) LOADA(10,sa) LOADA(11,sa) LOADA(12,sa) LOADB(8,sb)
  }
  // tail: 7th sv of this half, drain ladder
  WT(13, A[4],  B[0])  MF5(0)
  WT(11, A[5],  B[1])  MF5(1)
  WT(9,  A[6],  B[2])  MF5(2)
  WT(7,  A[7],  B[3])  MF5(3)
  WT(5,  A[8],  B[4])  MF5(4)
  WT(4,  A[9],  B[5])  MF5(5)
  WT(3,  A[10], B[6])  MF5(6)
  WT(2,  A[11], B[7])  MF5(7)
  WT(0,  A[12], B[8])  MF5(8)
  __syncthreads();

  // deterministic cross-wave fold in LDS (waves add sequentially)
  for (int z = tid; z < 5120; z += 256) fl[z] = 0.f;
  __syncthreads();
  for (int ww = 0; ww < 4; ++ww) {
    if (w == ww) {
#pragma unroll
      for (int k = 0; k < 5; ++k) {
        if (!(g == 3 && k == 4)) {    // g3 chain 4 duplicates i0=36: exclude
#pragma unroll
          for (int q = 0; q < 16; ++q)
            fl[k*1024 + q*64 + lane] += acc[k][q];
        }
      }
    }
    __syncthreads();
  }

  // emit 11 output rows [10g-1, 10g+9]; slabs [svh][uq][g&1] write-disjoint
  const int n = (tid >> 4) & 15;
  const int o = tid & 15;
  float* slab = partial + (svh*6 + uq*2 + (g & 1)) * OUT2;
  for (int ii = 0; ii < 11; ++ii) {
    const int i = 10*g - 1 + ii;
    if (i < 0 || i >= 37) continue;
    const int dd = ii - 1;
    float v;
    if (!(dd & 1)) {                  // diag: (uu,p)=(0,0)+(1,1)
      const int k = dd >> 1;
      v = F_LD(k, n, o) + F_LD(k, n+16, o+16);
    } else {
      v = 0.f;
      if (dd >= 1) v += F_LD((dd-1) >> 1, n+16, o);   // (1,0) from left chain
      const int kr = (dd+1) >> 1;
      if (kr <= 4) v += F_LD(kr, n, o+16);            // (0,1) from right chain
    }
    slab[(o*16 + n)*1369 + i*37 + j] = v;
  }
}

// ---------------- k3: reduce 12 partial slabs + scale (vectorized) -----------
__global__ __launch_bounds__(256) void k3_reduce(
    const float* __restrict__ partial, float* __restrict__ out2) {
  const int idx = blockIdx.x*256 + threadIdx.x;   // one float4 per thread
  if (idx >= OUT2/4) return;
  f32x4 s = {0.f, 0.f, 0.f, 0.f};
#pragma unroll
  for (int t = 0; t < 12; ++t) {
    f32x4 v = *(const f32x4*)(partial + t*OUT2 + idx*4);
    s[0] += v[0]; s[1] += v[1]; s[2] += v[2]; s[3] += v[3];
  }
  const float sc = 1.0f / 44944.0f;
  s[0] *= sc; s[1] *= sc; s[2] *= sc; s[3] *= sc;
  *(f32x4*)(out2 + idx*4) = s;
}

extern "C" void kernel_launch(void* const* d_in, const int* in_sizes, int n_in,
                              void* d_out, int out_size, void* d_ws, size_t ws_size,
                              hipStream_t stream) {
  (void)in_sizes; (void)n_in; (void)out_size; (void)ws_size;
  const float* x   = (const float*)d_in[0];
  const float* ft  = (const float*)d_in[1];
  const float* fnt = (const float*)d_in[2];
  float* out = (float*)d_out;
  char*  ws  = (char*)d_ws;
  unsigned char* Ximg3 = (unsigned char*)ws;
  unsigned char* Tmpl3 = (unsigned char*)(ws + TMPL_OFFB);
  float* partial = (float*)(ws + PART_OFFB);
  u16*   Xc      = (u16*)(ws + XC_OFFB);

  k1_conv<<<dim3(17, 16), 256, 0, stream>>>(x, ft, fnt, out, Xc);
  k1b_expand<<<2173, 256, 0, stream>>>(Xc, (unsigned char*)ws, partial);
  k2_corr<<<960, 256, 0, stream>>>(Ximg3, Tmpl3, partial);
  k3_reduce<<<343, 256, 0, stream>>>(partial, out + OUT1);
}

// Round 14
// 68.416 us; speedup vs baseline: 1.1299x; 1.1061x over previous
//
#include <hip/hip_runtime.h>
#include <hip/hip_fp8.h>
#include <cstdint>

typedef unsigned short u16;
typedef unsigned int   u32;
typedef unsigned long long u64;
typedef float  f32x16 __attribute__((ext_vector_type(16)));
typedef float  f32x4  __attribute__((ext_vector_type(4)));
typedef u32    u32x2  __attribute__((ext_vector_type(2)));
typedef u32    u32x4  __attribute__((ext_vector_type(4)));

#define OUT1 984064   // 16*248*248
#define OUT2 350464   // 16*16*37*37

// workspace layout (bytes) — fp8 edition (r8, session-best configuration)
// Ximg3: [d:8][vb:32][row:248][n:16][c:8] fp8  (col = d + 8*vb + c)
#define XD_STRIDE  1015808           // 32 vb * 31744
#define TMPL_OFFB  8126464
// Tmpl3: [vb:28][row:216][o:16][c:8] fp8       (col = 8*vb + c, zero-padded)
#define PART_OFFB  8900608
#define PART_ELEMS (6*OUT2)          // [3 uq][2 gp] partial slabs
#define XC_OFFB    17311744          // Xc: [c:16][row:248][col:264] bf16

// ---------------- k1: f32 conv + relu + normalize -> out1 + canonical bf16 Xc
__global__ __launch_bounds__(256) void k1_conv(
    const float* __restrict__ x, const float* __restrict__ ft,
    const float* __restrict__ fnt, float* __restrict__ out1,
    u16* __restrict__ Xc) {
  __shared__ float xt[24][25];
  __shared__ float wsm[1296];
  const int tid = threadIdx.x;
  const int lx = tid & 15, ly = tid >> 4;
  const int bx = blockIdx.x, by = blockIdx.y;
  for (int idx = tid; idx < 1296; idx += 256) {   // effw built in-block
    int c = idx / 81, s = idx - (idx / 81) * 81;
    wsm[idx] = (c < 8) ? 0.5f * (ft[c*162 + s] + ft[c*162 + 81 + s])
                       : fnt[(c-8)*81 + s];
  }
  for (int idx = tid; idx < 576; idx += 256) {
    int ry = idx / 24, rx = idx - ry * 24;
    int gy = by*16 + ry; gy = gy > 255 ? 255 : gy;
    int gx = bx*16 + rx; gx = gx > 255 ? 255 : gx;
    xt[ry][rx] = x[gy*256 + gx];
  }
  __syncthreads();
  const int xg = bx*16 + lx, yg = by*16 + ly;
  if (yg >= 248) return;
  float s[16];
#pragma unroll
  for (int c = 0; c < 16; ++c) s[c] = 0.f;
  const bool valid = (xg < 248);
  if (valid) {
#pragma unroll
    for (int u = 0; u < 9; ++u)
#pragma unroll
      for (int v = 0; v < 9; ++v) {
        float xv = xt[ly + u][lx + v];
#pragma unroll
        for (int c = 0; c < 16; ++c)
          s[c] = __builtin_fmaf(xv, wsm[c*81 + u*9 + v], s[c]);
      }
    float sum = 2.2204460492503131e-16f;  // EPS, matches reference
#pragma unroll
    for (int c = 0; c < 16; ++c) { s[c] = s[c] > 0.f ? s[c] : 0.f; sum += s[c]; }
    float inv = 1.f / sum;
#pragma unroll
    for (int c = 0; c < 16; ++c) s[c] *= inv;
  }
#pragma unroll
  for (int c = 0; c < 16; ++c) {
    u16 hb = 0;
    if (valid) {
      out1[c*61504 + yg*248 + xg] = s[c];
      u32 ub = __builtin_bit_cast(u32, s[c]);
      hb = (u16)((ub + 0x7fffu + ((ub >> 16) & 1u)) >> 16);  // bf16 RNE
    }
    if (xg < 264) Xc[(c*248 + yg)*264 + xg] = hb;  // cols 248..263 get zeros
  }
}

// ---------------- k1b: Xc(bf16) -> fp8 Ximg3 (8 shifts) + Tmpl3; zero partial
__device__ __forceinline__ u32 pk4_fp8(u32 b0, u32 b1) {
  // two u32 of packed bf16 (4 values) -> 4 fp8 e4m3 bytes (RNE via HIP type)
  float f0 = __builtin_bit_cast(float, b0 << 16);
  float f1 = __builtin_bit_cast(float, b0 & 0xFFFF0000u);
  float f2 = __builtin_bit_cast(float, b1 << 16);
  float f3 = __builtin_bit_cast(float, b1 & 0xFFFF0000u);
  __hip_fp8_e4m3 e0(f0), e1(f1), e2(f2), e3(f3);
  return (u32)e0.__x | ((u32)e1.__x << 8) | ((u32)e2.__x << 16) | ((u32)e3.__x << 24);
}

__global__ __launch_bounds__(256) void k1b_expand(
    const u16* __restrict__ Xc, unsigned char* __restrict__ ws8,
    float* __restrict__ partial) {
  const int cid = blockIdx.x*256 + threadIdx.x;
  for (int z = cid; z < PART_ELEMS; z += gridDim.x*256) partial[z] = 0.f;
  const u32* src = (const u32*)Xc;
  if (cid < 507904) {                  // Ximg3: 8d*32vb*248row*8npair chunks of 16B
    int np = cid & 7;
    int r1 = cid >> 3;
    int row = r1 % 248;
    int r2  = r1 / 248;
    int vb  = r2 & 31;
    int d   = r2 >> 5;
    int colb = (d & ~1) + 8*vb;        // even -> 4B-aligned dword index
    u32 wout[4];
#pragma unroll
    for (int h = 0; h < 2; ++h) {
      int n = 2*np + h;
      int so = (n*248 + row)*132 + (colb >> 1);
      u32 a0 = src[so], a1 = src[so+1], a2 = src[so+2], a3 = src[so+3], a4 = src[so+4];
      u32 b0, b1, b2, b3;
      if (d & 1) {                     // odd shift: 16-bit funnel
        b0 = (a0 >> 16) | (a1 << 16); b1 = (a1 >> 16) | (a2 << 16);
        b2 = (a2 >> 16) | (a3 << 16); b3 = (a3 >> 16) | (a4 << 16);
      } else { b0 = a0; b1 = a1; b2 = a2; b3 = a3; }
      wout[h*2]     = pk4_fp8(b0, b1);
      wout[h*2 + 1] = pk4_fp8(b2, b3);
    }
    u32x4 v = { wout[0], wout[1], wout[2], wout[3] };
    *(u32x4*)(ws8 + ((size_t)((d*32 + vb)*248 + row))*128 + np*16) = v;
  } else if (cid < 507904 + 48384) {   // Tmpl3: 28vb*216row*8npair chunks of 16B
    int t  = cid - 507904;
    int np = t & 7;
    int r1 = t >> 3;
    int tr = r1 % 216;
    int vb = r1 / 216;
    u32x4 v = {0u, 0u, 0u, 0u};
    if (tr < 212 && vb < 27) {
#pragma unroll
      for (int h = 0; h < 2; ++h) {
        int n = 2*np + h;
        int so = (n*248 + tr + 18)*132 + ((18 + 8*vb) >> 1);
        u32 b0 = src[so], b1 = src[so+1], b2 = src[so+2], b3 = src[so+3];
        if (vb == 26) { b2 = 0u; b3 = 0u; }   // cols 212..215 are pad
        v[h*2]     = pk4_fp8(b0, b1);
        v[h*2 + 1] = pk4_fp8(b2, b3);
      }
    }
    *(u32x4*)(ws8 + TMPL_OFFB + ((size_t)(vb*216 + tr))*128 + np*16) = v;
  }
}

// ---------------- k2: fp8 MFMA correlation, counted-vmcnt rotating pipeline --
// Session-best body (r8). Plateau ledger (all falsified by clean A/B):
// bytes (r8 -11%), lines (r8vs r11 ~0), inst count (r11 0), depth (r10 0),
// registers (r7 0), occupancy 1.7->3.5 waves/SIMD (r13 ~0), sc0 (r12 +7us),
// setprio (r5 spill), atomics emit (r9 +44us). k2 ~40us = 2.7x MFMA floor;
// residual cause not identifiable from available counters.
#define F_LD(k,m,c) fl[(k)*1024 + (((m)&3) + 4*((m)>>3))*64 + ((c) + 32*(((m)>>2)&1))]

#define LOADA(q,SO) asm volatile("buffer_load_dwordx2 %0, %1, %2, %3 offen" \
  : "=v"(A[q]) : "v"(voffA[q]), "s"(srdA), "s"(SO));
#define LOADB(t,SO) asm volatile("buffer_load_dwordx2 %0, %1, %2, %3 offen" \
  : "=v"(B[t]) : "v"(voffB[t]), "s"(srdB), "s"(SO));
#define WT(N,X,Y) asm volatile("s_waitcnt vmcnt(" #N ")" : "+v"(X), "+v"(Y) ::);
#define MF5(t) { long _bb = __builtin_bit_cast(long, B[t]); \
  acc[0]=__builtin_amdgcn_mfma_f32_32x32x16_fp8_fp8(__builtin_bit_cast(long,A[t+0]),_bb,acc[0],0,0,0); \
  acc[1]=__builtin_amdgcn_mfma_f32_32x32x16_fp8_fp8(__builtin_bit_cast(long,A[t+1]),_bb,acc[1],0,0,0); \
  acc[2]=__builtin_amdgcn_mfma_f32_32x32x16_fp8_fp8(__builtin_bit_cast(long,A[t+2]),_bb,acc[2],0,0,0); \
  acc[3]=__builtin_amdgcn_mfma_f32_32x32x16_fp8_fp8(__builtin_bit_cast(long,A[t+3]),_bb,acc[3],0,0,0); \
  acc[4]=__builtin_amdgcn_mfma_f32_32x32x16_fp8_fp8(__builtin_bit_cast(long,A[t+4]),_bb,acc[4],0,0,0); }

__global__ __launch_bounds__(256, 2) void k2_corr(
    const unsigned char* __restrict__ Ximg3, const unsigned char* __restrict__ Tmpl3,
    float* __restrict__ partial) {
  __shared__ float fl[5120];
  const int bid = blockIdx.x;
  const int d   = bid & 7;            // shift residue (XCD pinning heuristic)
  const int m0  = bid >> 3;           // 0..59
  const int jq  = m0 % 5;
  const int cmb = m0 / 5;             // 0..11
  const int g   = cmb & 3;
  const int uq  = cmb >> 2;           // 0..2
  const int j   = d + 8*jq;
  if (j >= 37) return;                // 36 idle pad blocks
  const int U0  = 72*uq;
  const int R0  = 10*g + U0;
  const int tid  = threadIdx.x;
  const int lane = tid & 63;
  const int w    = tid >> 6;
  const int fn16 = lane & 15;
  const int fuu  = (lane >> 4) & 1;
  const int fg   = lane >> 5;

  // SRDs (uniform bases); per-lane 32-bit voffsets; sv advance rides in soffset
  u64 pa = (u64)(Ximg3 + d*XD_STRIDE + jq*31744);
  u64 pb = (u64)(Tmpl3);
  u32x4 srdA = { (u32)pa, (u32)(pa >> 32), 0xFFFFFFFFu, 0x00020000u };
  u32x4 srdB = { (u32)pb, (u32)(pb >> 32), 0xFFFFFFFFu, 0x00020000u };
  int voffA[13], voffB[9];
#pragma unroll
  for (int q = 0; q < 13; ++q) {
    int r = R0 + fuu + 18*w + 2*q;
    if (r > 247) r = 247;             // clamped rows only ever pair with zero B
    voffA[q] = fg*31744 + fn16*8 + r*128;
  }
#pragma unroll
  for (int t = 0; t < 9; ++t)
    voffB[t] = fg*27648 + fn16*8 + (U0 + fuu + 18*w + 2*t)*128;

  f32x16 acc[5];
#pragma unroll
  for (int k = 0; k < 5; ++k)
#pragma unroll
    for (int q = 0; q < 16; ++q) acc[k][q] = 0.f;

  u32x2 A[13], B[9];
  // prologue (sv=0), issue order P0..P8 (the vmcnt ladder depends on it)
  { int sa = 0, sb = 0;
    LOADA(0,sa) LOADB(0,sb) LOADA(1,sa) LOADB(1,sb)
    LOADA(2,sa) LOADB(2,sb) LOADA(3,sa) LOADB(3,sb)
    LOADA(4,sa) LOADB(4,sb) LOADA(5,sa) LOADB(5,sb)
    LOADA(6,sa) LOADB(6,sb) LOADA(7,sa) LOADB(7,sb)
    LOADA(8,sa) LOADA(9,sa) LOADA(10,sa) LOADA(11,sa) LOADA(12,sa) LOADB(8,sb) }

#pragma unroll 1
  for (int sv = 0; sv < 13; ++sv) {   // consume sv, prefetch sv+1 in place
    const int sa = (sv + 1)*63488, sb = (sv + 1)*55296;
    WT(13, A[4],  B[0])  MF5(0) LOADA(0,sa) LOADB(0,sb)
    WT(13, A[5],  B[1])  MF5(1) LOADA(1,sa) LOADB(1,sb)
    WT(13, A[6],  B[2])  MF5(2) LOADA(2,sa) LOADB(2,sb)
    WT(13, A[7],  B[3])  MF5(3) LOADA(3,sa) LOADB(3,sb)
    WT(13, A[8],  B[4])  MF5(4) LOADA(4,sa) LOADB(4,sb)
    WT(14, A[9],  B[5])  MF5(5) LOADA(5,sa) LOADB(5,sb)
    WT(15, A[10], B[6])  MF5(6) LOADA(6,sa) LOADB(6,sb)
    WT(16, A[11], B[7])  MF5(7) LOADA(7,sa) LOADB(7,sb)
    WT(16, A[12], B[8])  MF5(8)
    LOADA(8,sa) LOADA(9,sa) LOADA(10,sa) LOADA(11,sa) LOADA(12,sa) LOADB(8,sb)
  }
  // tail: sv=13, drain ladder
  WT(13, A[4],  B[0])  MF5(0)
  WT(11, A[5],  B[1])  MF5(1)
  WT(9,  A[6],  B[2])  MF5(2)
  WT(7,  A[7],  B[3])  MF5(3)
  WT(5,  A[8],  B[4])  MF5(4)
  WT(4,  A[9],  B[5])  MF5(5)
  WT(3,  A[10], B[6])  MF5(6)
  WT(2,  A[11], B[7])  MF5(7)
  WT(0,  A[12], B[8])  MF5(8)
  __syncthreads();

  // deterministic cross-wave fold in LDS (waves add sequentially)
  for (int z = tid; z < 5120; z += 256) fl[z] = 0.f;
  __syncthreads();
  for (int ww = 0; ww < 4; ++ww) {
    if (w == ww) {
#pragma unroll
      for (int k = 0; k < 5; ++k) {
        if (!(g == 3 && k == 4)) {    // g3 chain 4 duplicates i0=36: exclude
#pragma unroll
          for (int q = 0; q < 16; ++q)
            fl[k*1024 + q*64 + lane] += acc[k][q];
        }
      }
    }
    __syncthreads();
  }

  // emit 11 output rows [10g-1, 10g+9]; slabs [uq][g&1] are write-disjoint
  const int n = (tid >> 4) & 15;
  const int o = tid & 15;
  float* slab = partial + (uq*2 + (g & 1)) * OUT2;
  for (int ii = 0; ii < 11; ++ii) {
    const int i = 10*g - 1 + ii;
    if (i < 0 || i >= 37) continue;
    const int dd = ii - 1;
    float v;
    if (!(dd & 1)) {                  // diag: (uu,p)=(0,0)+(1,1)
      const int k = dd >> 1;
      v = F_LD(k, n, o) + F_LD(k, n+16, o+16);
    } else {
      v = 0.f;
      if (dd >= 1) v += F_LD((dd-1) >> 1, n+16, o);   // (1,0) from left chain
      const int kr = (dd+1) >> 1;
      if (kr <= 4) v += F_LD(kr, n, o+16);            // (0,1) from right chain
    }
    slab[(o*16 + n)*1369 + i*37 + j] = v;
  }
}

// ---------------- k3: reduce 6 partial slabs + scale (vectorized) ------------
__global__ __launch_bounds__(256) void k3_reduce(
    const float* __restrict__ partial, float* __restrict__ out2) {
  const int idx = blockIdx.x*256 + threadIdx.x;   // one float4 per thread
  if (idx >= OUT2/4) return;
  f32x4 s = {0.f, 0.f, 0.f, 0.f};
#pragma unroll
  for (int t = 0; t < 6; ++t) {
    f32x4 v = *(const f32x4*)(partial + t*OUT2 + idx*4);
    s[0] += v[0]; s[1] += v[1]; s[2] += v[2]; s[3] += v[3];
  }
  const float sc = 1.0f / 44944.0f;
  s[0] *= sc; s[1] *= sc; s[2] *= sc; s[3] *= sc;
  *(f32x4*)(out2 + idx*4) = s;
}

extern "C" void kernel_launch(void* const* d_in, const int* in_sizes, int n_in,
                              void* d_out, int out_size, void* d_ws, size_t ws_size,
                              hipStream_t stream) {
  (void)in_sizes; (void)n_in; (void)out_size; (void)ws_size;
  const float* x   = (const float*)d_in[0];
  const float* ft  = (const float*)d_in[1];
  const float* fnt = (const float*)d_in[2];
  float* out = (float*)d_out;
  char*  ws  = (char*)d_ws;
  unsigned char* Ximg3 = (unsigned char*)ws;
  unsigned char* Tmpl3 = (unsigned char*)(ws + TMPL_OFFB);
  float* partial = (float*)(ws + PART_OFFB);
  u16*   Xc      = (u16*)(ws + XC_OFFB);

  k1_conv<<<dim3(17, 16), 256, 0, stream>>>(x, ft, fnt, out, Xc);
  k1b_expand<<<2173, 256, 0, stream>>>(Xc, (unsigned char*)ws, partial);
  k2_corr<<<480, 256, 0, stream>>>(Ximg3, Tmpl3, partial);
  k3_reduce<<<343, 256, 0, stream>>>(partial, out + OUT1);
}